// Round 1
// baseline (187.919 us; speedup 1.0000x reference)
//
#include <hip/hip_runtime.h>

// Problem constants (from reference): B=4, N=2048, IN_F=512, HEADS=8, D=64
#define BB   4
#define NN   2048
#define INF  512
#define HH   8
#define DD   64
#define BH   (BB*HH)   // 32
#define NCK  16        // 128-row chunks per (b,h)
#define CKS  128       // chunk size
#define KSP  2         // k-split for V GEMM

// ============================================================================
// A[b,h,i,j] = softmax_j( leaky_relu(q_j + k_i) ), H = A @ V.
// exp(leaky(x)) is piecewise multiplicative; sort j by q_j and the softmax
// collapses to prefix sums + binary search. O(N·D).
// R9 calibration: LDS pipe is per-CU shared (~85B/cyc) -> GEMM LDS bytes/flop
// sets the floor. R10: k_v at 0.5B/flop (W-only LDS, b128/k; X via global
// broadcast f4), KSP=2 so Vpart traffic 8.4MB; k_off folded into k_out's
// LDS preamble. Harness 0xAA ws-poison (~90us) is inside dur_us, untouchable.
// R11: bitonic k_sort (32 blocks, 66 LDS phases, ~15us modeled) replaced by
// O(N^2) rank-compute: tie-proof u64 keys (orderable_u32(q)<<32 | j) built in
// k_vred; k_rank does 2048 scalar-cached v_cmp_lt_u64 per thread (~4.5us,
// 256 blocks, no barriers) and scatters sq/idx directly.
// ============================================================================

// ---- Kernel 1a: V partials. block = 32 rows x 64 cols x 256 k (one half) ---
__global__ __launch_bounds__(256) void k_v(
    const float* __restrict__ X, const float* __restrict__ Wv,
    float* __restrict__ Vpart)   // [KSP][BB*NN][DD]
{
  __shared__ float Ws[64][68];      // [k][n] chunk, padded — 17.4 KB
  const int t  = threadIdx.x;
  const int tc = t & 15;            // col quad -> cols 4tc..4tc+3
  const int tr = t >> 4;            // row pair -> rows 2tr, 2tr+1
  const int rg = blockIdx.x >> 1;   // 0..255: 32-row group
  const int kh = blockIdx.x & 1;    // k half
  const int r0 = rg * 32;
  const int k0 = kh * 256;
  float acc[2][4] = {{0.f}};

  for (int kc = 0; kc < 256; kc += 64) {
    __syncthreads();
    #pragma unroll
    for (int i = 0; i < 4; i++) {    // stage 64k x 64n, coalesced f4
      const int e4 = t + i * 256;
      const int k  = e4 >> 4;
      const int n4 = (e4 & 15) * 4;
      *(float4*)(&Ws[k][n4]) = *(const float4*)(Wv + (size_t)(k0 + kc + k) * DD + n4);
    }
    __syncthreads();
    const float* xp0 = X + (size_t)(r0 + tr * 2) * INF + k0 + kc;
    const float* xp1 = xp0 + INF;
    #pragma unroll 8
    for (int kk = 0; kk < 64; kk += 4) {
      const float4 xa = *(const float4*)(xp0 + kk);   // 16 lanes/addr bcast
      const float4 xb = *(const float4*)(xp1 + kk);
      #pragma unroll
      for (int j = 0; j < 4; j++) {
        const float4 w4 = *(const float4*)(&Ws[kk + j][tc * 4]);
        const float xaj = (j == 0) ? xa.x : (j == 1) ? xa.y : (j == 2) ? xa.z : xa.w;
        const float xbj = (j == 0) ? xb.x : (j == 1) ? xb.y : (j == 2) ? xb.z : xb.w;
        acc[0][0] += xaj * w4.x;  acc[0][1] += xaj * w4.y;
        acc[0][2] += xaj * w4.z;  acc[0][3] += xaj * w4.w;
        acc[1][0] += xbj * w4.x;  acc[1][1] += xbj * w4.y;
        acc[1][2] += xbj * w4.z;  acc[1][3] += xbj * w4.w;
      }
    }
  }
  float* vp = Vpart + ((size_t)kh * (BB*NN) + r0 + tr * 2) * DD + tc * 4;
  #pragma unroll
  for (int r = 0; r < 2; r++) {
    float4 o;  o.x = acc[r][0];  o.y = acc[r][1];  o.z = acc[r][2];  o.w = acc[r][3];
    *(float4*)(vp + (size_t)r * DD) = o;
  }
}

// -------- Kernel 1b: V = sum(partials)+bv ; q,k scalar scores + u64 q-keys --
__global__ __launch_bounds__(256) void k_vred(
    const float* __restrict__ Vpart, const float* __restrict__ bv,
    const float* __restrict__ Wq, const float* __restrict__ bq,
    const float* __restrict__ Wk, const float* __restrict__ bk,
    float* __restrict__ V, float* __restrict__ qsg, float* __restrict__ ksg,
    unsigned long long* __restrict__ qk64)
{
  __shared__ float Vs[16][DD + 1];
  const int t  = threadIdx.x;
  const size_t e0 = ((size_t)blockIdx.x * 256 + t) * 4;
  const size_t STR = (size_t)BB * NN * DD;
  float4 a = *(const float4*)(Vpart + e0);
  #pragma unroll
  for (int p = 1; p < KSP; p++) {
    const float4 b = *(const float4*)(Vpart + (size_t)p * STR + e0);
    a.x += b.x;  a.y += b.y;  a.z += b.z;  a.w += b.w;
  }
  const float4 bb = *(const float4*)(bv + (e0 & 63));
  a.x += bb.x;  a.y += bb.y;  a.z += bb.z;  a.w += bb.w;
  *(float4*)(V + e0) = a;
  const int lrow = t >> 4;
  const int lcol = (t * 4) & 63;
  Vs[lrow][lcol]   = a.x;  Vs[lrow][lcol+1] = a.y;
  Vs[lrow][lcol+2] = a.z;  Vs[lrow][lcol+3] = a.w;
  __syncthreads();
  const int row = t >> 4;
  const int h   = t & 7;
  const bool isK = (t & 8) != 0;
  const float* W = isK ? Wk : Wq;
  float s = isK ? bk[h] : bq[h];
  #pragma unroll 8
  for (int dd = 0; dd < DD; dd++) s += Vs[row][dd] * W[dd*HH + h];
  const int grow = blockIdx.x * 16 + row;
  const int b = grow >> 11, n = grow & (NN - 1);
  (isK ? ksg : qsg)[(b*HH + h) * NN + n] = s;
  if (!isK) {
    // tie-proof orderable key: ascending u64 order == ascending (float, idx)
    unsigned u = __float_as_uint(s);
    u = (u & 0x80000000u) ? ~u : (u | 0x80000000u);
    qk64[(size_t)(b*HH + h) * NN + n] =
        ((unsigned long long)u << 32) | (unsigned)n;
  }
}

// -------- Kernel 2: O(N^2) rank + scatter (replaces bitonic sort) -----------
// 256 blocks x 256 threads, one j per thread. Key table is block-uniform ->
// scalar-cache s_loads, double-buffered (A/Bt) so 16 v_cmp+addc cover latency.
__global__ __launch_bounds__(256) void k_rank(
    const unsigned long long* __restrict__ qk64,
    const float* __restrict__ q,
    float* __restrict__ sqs, unsigned short* __restrict__ idxg)
{
  const int t  = threadIdx.x;
  const int bh = blockIdx.x >> 3;
  const int j  = ((blockIdx.x & 7) << 8) | t;
  const unsigned long long* __restrict__ kb = qk64 + (size_t)bh * NN;
  const unsigned long long kj = kb[j];          // divergent, coalesced
  int c0 = 0, c1 = 0, c2 = 0, c3 = 0;
  unsigned long long A[8], Bt[8];
  #pragma unroll
  for (int x = 0; x < 8; x++) A[x] = kb[x];     // uniform -> s_load
  for (int l = 0; l < NN; l += 8) {
    const int ln = (l + 8) & (NN - 1);          // wraps (harmless) on last
    #pragma unroll
    for (int x = 0; x < 8; x++) Bt[x] = kb[ln + x];   // prefetch next batch
    c0 += (A[0] < kj);  c1 += (A[1] < kj);
    c2 += (A[2] < kj);  c3 += (A[3] < kj);
    c0 += (A[4] < kj);  c1 += (A[5] < kj);
    c2 += (A[6] < kj);  c3 += (A[7] < kj);
    #pragma unroll
    for (int x = 0; x < 8; x++) A[x] = Bt[x];   // SALU copy, co-issues
  }
  const int rank = (c0 + c1) + (c2 + c3);       // unique: keys are distinct
  sqs [bh*NN + rank] = q[bh*NN + j];
  idxg[bh*NN + rank] = (unsigned short)j;
}

// -------- Kernel 3: hierarchical scan — chunk-local prefixes + chunk sums ----
__global__ __launch_bounds__(256) void k_scan(
    const float* __restrict__ sq, const unsigned short* __restrict__ idxg,
    const float* __restrict__ V,
    float* __restrict__ P1, float* __restrict__ P2,
    float* __restrict__ l1, float* __restrict__ l2,
    float* __restrict__ S1g, float* __restrict__ S2g,
    float* __restrict__ SL1, float* __restrict__ SL2)
{
  __shared__ float vstash[4][32][DD];   // 32 KB, wave-local slices
  __shared__ float ss1[4][64], ss2[4][64], sl1[4], sl2[4];
  const int t  = threadIdx.x;
  const int bh = blockIdx.x >> 4;
  const int ck = blockIdx.x & 15;
  const int d  = t & 63, g = t >> 6;
  const int r0 = ck*CKS + g*32;
  const float* Vb  = V + (size_t)(bh >> 3) * NN * DD;
  const float* sqb = sq + bh*NN;
  const unsigned short* ib = idxg + bh*NN;
  float a1 = 0.f, a2 = 0.f, s1 = 0.f, s2 = 0.f;
  #pragma unroll 8
  for (int rr = 0; rr < 32; rr++) {
    const int r = r0 + rr;
    const float qv = sqb[r];
    const float e1 = __expf(qv), e2 = __expf(0.01f*qv);
    const float v  = Vb[(size_t)ib[r]*DD + d];
    vstash[g][rr][d] = v;               // same-wave, in-order
    a1 += e1*v;  a2 += e2*v;  s1 += e1;  s2 += e2;
  }
  ss1[g][d] = a1;  ss2[g][d] = a2;
  if (d == 0) { sl1[g] = s1;  sl2[g] = s2; }
  __syncthreads();
  float o1 = 0.f, o2 = 0.f, lo1 = 0.f, lo2 = 0.f;
  for (int gg = 0; gg < g; gg++) { o1 += ss1[gg][d]; o2 += ss2[gg][d]; lo1 += sl1[gg]; lo2 += sl2[gg]; }
  if (g == 0) {   // chunk totals (now in d_ws — no d_out aliasing)
    S1g[(bh*NCK + ck)*64 + d] = ss1[0][d]+ss1[1][d]+ss1[2][d]+ss1[3][d];
    S2g[(bh*NCK + ck)*64 + d] = ss2[0][d]+ss2[1][d]+ss2[2][d]+ss2[3][d];
    if (d == 0) {
      SL1[bh*NCK + ck] = sl1[0]+sl1[1]+sl1[2]+sl1[3];
      SL2[bh*NCK + ck] = sl2[0]+sl2[1]+sl2[2]+sl2[3];
    }
  }
  // pass 2: exclusive chunk-local prefixes; V from LDS stash
  a1 = o1; a2 = o2; s1 = lo1; s2 = lo2;
  float* P1b = P1 + (size_t)bh*NN*DD;
  float* P2b = P2 + (size_t)bh*NN*DD;
  #pragma unroll 8
  for (int rr = 0; rr < 32; rr++) {
    const int r = r0 + rr;
    const float qv = sqb[r];
    const float e1 = __expf(qv), e2 = __expf(0.01f*qv);
    const float v  = vstash[g][rr][d];
    P1b[(size_t)r*DD + d] = a1;
    P2b[(size_t)r*DD + d] = a2;
    if (d == 0) { l1[bh*NN + r] = s1;  l2[bh*NN + r] = s2; }
    a1 += e1*v;  a2 += e2*v;  s1 += e1;  s2 += e2;
  }
}

// ------- Kernel 4: offsets-in-LDS preamble + 64-ary search + write ----------
__global__ __launch_bounds__(256) void k_out(
    const float* __restrict__ sq, const float* __restrict__ ksg,
    const float* __restrict__ P1, const float* __restrict__ P2,
    const float* __restrict__ S1g, const float* __restrict__ S2g,
    const float* __restrict__ SL1, const float* __restrict__ SL2,
    const float* __restrict__ l1, const float* __restrict__ l2,
    float* __restrict__ out)
{
  __shared__ float Of1[NCK + 1][64], Of2[NCK + 1][64];
  __shared__ float Lo1[NCK + 1], Lo2[NCK + 1];
  const int t   = threadIdx.x;
  const int bh  = blockIdx.x >> 7;                       // 32 bh x 128 blocks
  const int loc = blockIdx.x & 127;
  const int w   = t >> 6;
  const int d   = t & 63;                                // lane id
  const int i0  = loc*16 + w*4;                          // 4 i's per wave
  const int b   = bh >> 3, h = bh & 7;

  // preamble: exclusive prefix of the 16 chunk sums (L2-hot, redundant/block)
  if (t < 64) {
    float a = 0.f;
    for (int ck = 0; ck < NCK; ck++) {
      Of1[ck][t] = a;  a += S1g[(bh*NCK + ck)*64 + t];
    }
    Of1[NCK][t] = a;
  } else if (t < 128) {
    const int dd = t - 64;
    float a = 0.f;
    for (int ck = 0; ck < NCK; ck++) {
      Of2[ck][dd] = a;  a += S2g[(bh*NCK + ck)*64 + dd];
    }
    Of2[NCK][dd] = a;
  } else if (t == 128) {
    float a = 0.f;
    for (int ck = 0; ck < NCK; ck++) { Lo1[ck] = a;  a += SL1[bh*NCK + ck]; }
    Lo1[NCK] = a;
  } else if (t == 129) {
    float a = 0.f;
    for (int ck = 0; ck < NCK; ck++) { Lo2[ck] = a;  a += SL2[bh*NCK + ck]; }
    Lo2[NCK] = a;
  }
  __syncthreads();

  const float* s = sq + bh*NN;
  const float probe = s[d*32 + 31];                      // shared round-1 table
  const float T1  = Of1[NCK][d];
  const float Lt1 = Lo1[NCK];
  const size_t base = (size_t)bh * NN * DD;

  float kv[4], tt[4];
  int pos[4];
  #pragma unroll
  for (int u = 0; u < 4; u++) { kv[u] = ksg[bh*NN + i0 + u];  tt[u] = -kv[u]; }
  #pragma unroll
  for (int u = 0; u < 4; u++) {
    const unsigned long long m1 = __ballot(probe <= tt[u]);
    const int c1 = __popcll(m1);
    if (c1 == 64) pos[u] = NN;
    else {
      const unsigned long long m2 = __ballot(s[c1*32 + (d & 31)] <= tt[u]);
      pos[u] = c1*32 + (__popcll(m2) >> 1);
    }
  }
  #pragma unroll
  for (int u = 0; u < 4; u++) {
    const float ek  = __expf(kv[u]);
    const float ek2 = __expf(0.01f * kv[u]);
    float p1v, p2v, q1v, q2v;
    if (pos[u] < NN) {   // wave-uniform
      const int ch = pos[u] >> 7;
      p1v = P1[base + (size_t)pos[u]*DD + d] + Of1[ch][d];
      p2v = P2[base + (size_t)pos[u]*DD + d] + Of2[ch][d];
      q1v = l1[bh*NN + pos[u]] + Lo1[ch];
      q2v = l2[bh*NN + pos[u]] + Lo2[ch];
    } else {
      p1v = T1;   p2v = Of2[NCK][d];
      q1v = Lt1;  q2v = Lo2[NCK];
    }
    const float num = ek * (T1 - p1v)  + ek2 * p2v;
    const float den = ek * (Lt1 - q1v) + ek2 * q2v;
    out[((size_t)(b*NN + i0 + u)) * (HH*DD) + h*DD + d] = num / den;
  }
}

extern "C" void kernel_launch(void* const* d_in, const int* in_sizes, int n_in,
                              void* d_out, int out_size, void* d_ws, size_t ws_size,
                              hipStream_t stream)
{
  (void)in_sizes; (void)n_in; (void)out_size; (void)ws_size;
  const float* X  = (const float*)d_in[0];
  const float* Wv = (const float*)d_in[1];
  const float* bv = (const float*)d_in[2];
  const float* Wq = (const float*)d_in[3];
  const float* bq = (const float*)d_in[4];
  const float* Wk = (const float*)d_in[5];
  const float* bk = (const float*)d_in[6];
  float* out = (float*)d_out;

  // workspace carve-up (~38 MB, within proven budget)
  float* w = (float*)d_ws;
  float* V     = w;  w += (size_t)BB*NN*DD;        // 524288
  float* qsg   = w;  w += BH*NN;                   // raw q (unsorted)
  float* ksg   = w;  w += BH*NN;
  float* l1    = w;  w += BH*NN;
  float* l2    = w;  w += BH*NN;
  unsigned short* idxg = (unsigned short*)w;  w += BH*NN/2;
  float* S1g   = w;  w += (size_t)BH*NCK*DD;       // 32768 (in ws, not d_out)
  float* S2g   = w;  w += (size_t)BH*NCK*DD;
  float* SL1   = w;  w += BH*NCK;
  float* SL2   = w;  w += BH*NCK;
  float* sqs   = w;  w += BH*NN;                   // sorted q (rank-scattered)
  unsigned long long* qk64 = (unsigned long long*)w;  w += BH*NN*2;  // u64 keys
  float* P1    = w;  w += (size_t)BH*NN*DD;        // 16.8 MB
  float* P2    = w;  w += (size_t)BH*NN*DD;

  // V partials alias P1 (dead until k_scan): KSP x 2.1MB = 4.2 MB < sizeof(P1)
  float* Vpart = P1;

  k_v    <<<512, 256, 0, stream>>>(X, Wv, Vpart);
  k_vred <<<512, 256, 0, stream>>>(Vpart, bv, Wq, bq, Wk, bk, V, qsg, ksg, qk64);
  k_rank <<<BH*8, 256, 0, stream>>>(qk64, qsg, sqs, idxg);
  k_scan <<<BH*NCK, 256, 0, stream>>>(sqs, idxg, V, P1, P2, l1, l2, S1g, S2g, SL1, SL2);
  k_out  <<<BH*128, 256, 0, stream>>>(sqs, ksg, P1, P2, S1g, S2g, SL1, SL2, l1, l2, out);
}

// Round 2
// 135.668 us; speedup vs baseline: 1.3851x; 1.3851x over previous
//
#include <hip/hip_runtime.h>

// Problem constants (from reference): B=4, N=2048, IN_F=512, HEADS=8, D=64
#define BB   4
#define NN   2048
#define INF  512
#define HH   8
#define DD   64
#define BH   (BB*HH)   // 32
#define NCK  16        // 128-row chunks per (b,h)
#define CKS  128       // chunk size
#define KSP  2         // k-split for V GEMM

// ============================================================================
// A[b,h,i,j] = softmax_j( leaky_relu(q_j + k_i) ), H = A @ V.
// exp(leaky(x)) is piecewise multiplicative; sort j by q_j and the softmax
// collapses to prefix sums + binary search. O(N·D).
// R9 calibration: LDS pipe is per-CU shared (~85B/cyc) -> GEMM LDS bytes/flop
// sets the floor. R10: k_v at 0.5B/flop (W-only LDS, b128/k; X via global
// broadcast f4), KSP=2 so Vpart traffic 8.4MB. Harness 0xAA ws-poison
// (~90us) is inside dur_us, untouchable.
// R11 FAILED: SMEM-fed O(N^2) rank = 66us. 1 wave/SIMD + per-iter
// lgkmcnt(0) drain on the s_load batch -> full L2 latency exposed per 8
// keys. Lesson: SMEM prefetch pipelining is compiler-hostile at occ=1.
// R12: LDS-fed rank. Stage 16KB key table/block; thread = 4 j's x 512-key
// quarter (K=4 split, LDS cnt combine). ds_read_b128 broadcast feeds 16
// VALU ops -> VALU-bound ~4us, no barriers in hot loop, no SMEM.
// ============================================================================

// ---- Kernel 1a: V partials. block = 32 rows x 64 cols x 256 k (one half) ---
__global__ __launch_bounds__(256) void k_v(
    const float* __restrict__ X, const float* __restrict__ Wv,
    float* __restrict__ Vpart)   // [KSP][BB*NN][DD]
{
  __shared__ float Ws[64][68];      // [k][n] chunk, padded — 17.4 KB
  const int t  = threadIdx.x;
  const int tc = t & 15;            // col quad -> cols 4tc..4tc+3
  const int tr = t >> 4;            // row pair -> rows 2tr, 2tr+1
  const int rg = blockIdx.x >> 1;   // 0..255: 32-row group
  const int kh = blockIdx.x & 1;    // k half
  const int r0 = rg * 32;
  const int k0 = kh * 256;
  float acc[2][4] = {{0.f}};

  for (int kc = 0; kc < 256; kc += 64) {
    __syncthreads();
    #pragma unroll
    for (int i = 0; i < 4; i++) {    // stage 64k x 64n, coalesced f4
      const int e4 = t + i * 256;
      const int k  = e4 >> 4;
      const int n4 = (e4 & 15) * 4;
      *(float4*)(&Ws[k][n4]) = *(const float4*)(Wv + (size_t)(k0 + kc + k) * DD + n4);
    }
    __syncthreads();
    const float* xp0 = X + (size_t)(r0 + tr * 2) * INF + k0 + kc;
    const float* xp1 = xp0 + INF;
    #pragma unroll 8
    for (int kk = 0; kk < 64; kk += 4) {
      const float4 xa = *(const float4*)(xp0 + kk);   // 16 lanes/addr bcast
      const float4 xb = *(const float4*)(xp1 + kk);
      #pragma unroll
      for (int j = 0; j < 4; j++) {
        const float4 w4 = *(const float4*)(&Ws[kk + j][tc * 4]);
        const float xaj = (j == 0) ? xa.x : (j == 1) ? xa.y : (j == 2) ? xa.z : xa.w;
        const float xbj = (j == 0) ? xb.x : (j == 1) ? xb.y : (j == 2) ? xb.z : xb.w;
        acc[0][0] += xaj * w4.x;  acc[0][1] += xaj * w4.y;
        acc[0][2] += xaj * w4.z;  acc[0][3] += xaj * w4.w;
        acc[1][0] += xbj * w4.x;  acc[1][1] += xbj * w4.y;
        acc[1][2] += xbj * w4.z;  acc[1][3] += xbj * w4.w;
      }
    }
  }
  float* vp = Vpart + ((size_t)kh * (BB*NN) + r0 + tr * 2) * DD + tc * 4;
  #pragma unroll
  for (int r = 0; r < 2; r++) {
    float4 o;  o.x = acc[r][0];  o.y = acc[r][1];  o.z = acc[r][2];  o.w = acc[r][3];
    *(float4*)(vp + (size_t)r * DD) = o;
  }
}

// -------- Kernel 1b: V = sum(partials)+bv ; q,k scalar scores + u64 q-keys --
__global__ __launch_bounds__(256) void k_vred(
    const float* __restrict__ Vpart, const float* __restrict__ bv,
    const float* __restrict__ Wq, const float* __restrict__ bq,
    const float* __restrict__ Wk, const float* __restrict__ bk,
    float* __restrict__ V, float* __restrict__ qsg, float* __restrict__ ksg,
    unsigned long long* __restrict__ qk64)
{
  __shared__ float Vs[16][DD + 1];
  const int t  = threadIdx.x;
  const size_t e0 = ((size_t)blockIdx.x * 256 + t) * 4;
  const size_t STR = (size_t)BB * NN * DD;
  float4 a = *(const float4*)(Vpart + e0);
  #pragma unroll
  for (int p = 1; p < KSP; p++) {
    const float4 b = *(const float4*)(Vpart + (size_t)p * STR + e0);
    a.x += b.x;  a.y += b.y;  a.z += b.z;  a.w += b.w;
  }
  const float4 bb = *(const float4*)(bv + (e0 & 63));
  a.x += bb.x;  a.y += bb.y;  a.z += bb.z;  a.w += bb.w;
  *(float4*)(V + e0) = a;
  const int lrow = t >> 4;
  const int lcol = (t * 4) & 63;
  Vs[lrow][lcol]   = a.x;  Vs[lrow][lcol+1] = a.y;
  Vs[lrow][lcol+2] = a.z;  Vs[lrow][lcol+3] = a.w;
  __syncthreads();
  const int row = t >> 4;
  const int h   = t & 7;
  const bool isK = (t & 8) != 0;
  const float* W = isK ? Wk : Wq;
  float s = isK ? bk[h] : bq[h];
  #pragma unroll 8
  for (int dd = 0; dd < DD; dd++) s += Vs[row][dd] * W[dd*HH + h];
  const int grow = blockIdx.x * 16 + row;
  const int b = grow >> 11, n = grow & (NN - 1);
  (isK ? ksg : qsg)[(b*HH + h) * NN + n] = s;
  if (!isK) {
    // tie-proof orderable key: ascending u64 order == ascending (float, idx)
    unsigned u = __float_as_uint(s);
    u = (u & 0x80000000u) ? ~u : (u | 0x80000000u);
    qk64[(size_t)(b*HH + h) * NN + n] =
        ((unsigned long long)u << 32) | (unsigned)n;
  }
}

// -------- Kernel 2: LDS-fed O(N^2) rank + scatter ---------------------------
// 256 blocks x 256 threads. Block = (bh, 256-j slab). Stage all 2048 keys in
// LDS (16KB); thread = (jq = t&63 -> 4 consecutive j's, kq = t>>6 -> 512-key
// quarter). Broadcast ds_read_b128 (2 keys) feeds 8 u64-cmps -> VALU-bound.
// Partial counts combined via LDS, wave 0 scatters. q recovered from key.
__global__ __launch_bounds__(256) void k_rank(
    const unsigned long long* __restrict__ qk64,
    float* __restrict__ sqs, unsigned short* __restrict__ idxg)
{
  __shared__ __align__(16) unsigned long long keys[NN];  // 16 KB
  __shared__ int cnt[4][256];                            // 4 KB
  const int t  = threadIdx.x;
  const int bh = blockIdx.x >> 3;
  const int jq = t & 63;
  const int kq = t >> 6;
  const unsigned long long* __restrict__ kb = qk64 + (size_t)bh * NN;

  // stage: 1024 x 16B, coalesced
  {
    const ulonglong2* __restrict__ g2 = (const ulonglong2*)kb;
    ulonglong2* s2 = (ulonglong2*)keys;
    #pragma unroll
    for (int x = 0; x < 4; x++) s2[t + 256 * x] = g2[t + 256 * x];
  }
  __syncthreads();

  const int jg = ((blockIdx.x & 7) << 8) | (jq << 2);    // first of 4 j's
  const unsigned long long kj0 = keys[jg];
  const unsigned long long kj1 = keys[jg + 1];
  const unsigned long long kj2 = keys[jg + 2];
  const unsigned long long kj3 = keys[jg + 3];

  const ulonglong2* __restrict__ k2 = (const ulonglong2*)(keys + kq * 512);
  int c0 = 0, c1 = 0, c2 = 0, c3 = 0;
  #pragma unroll 8
  for (int l = 0; l < 256; l++) {            // 512 keys, 2 per b128
    const ulonglong2 kk = k2[l];
    c0 += (kk.x < kj0) + (kk.y < kj0);
    c1 += (kk.x < kj1) + (kk.y < kj1);
    c2 += (kk.x < kj2) + (kk.y < kj2);
    c3 += (kk.x < kj3) + (kk.y < kj3);
  }
  cnt[kq][0 * 64 + jq] = c0;   // [u*64+jq]: lane-stride-1, conflict-free
  cnt[kq][1 * 64 + jq] = c1;
  cnt[kq][2 * 64 + jq] = c2;
  cnt[kq][3 * 64 + jq] = c3;
  __syncthreads();

  if (kq == 0) {
    #pragma unroll
    for (int u = 0; u < 4; u++) {
      const int rank = cnt[0][u * 64 + jq] + cnt[1][u * 64 + jq]
                     + cnt[2][u * 64 + jq] + cnt[3][u * 64 + jq];
      const unsigned long long kj = keys[jg + u];
      const unsigned uo = (unsigned)(kj >> 32);
      const unsigned ur = (uo & 0x80000000u) ? (uo & 0x7fffffffu) : ~uo;
      sqs [bh * NN + rank] = __uint_as_float(ur);
      idxg[bh * NN + rank] = (unsigned short)(jg + u);
    }
  }
}

// -------- Kernel 3: hierarchical scan — chunk-local prefixes + chunk sums ----
__global__ __launch_bounds__(256) void k_scan(
    const float* __restrict__ sq, const unsigned short* __restrict__ idxg,
    const float* __restrict__ V,
    float* __restrict__ P1, float* __restrict__ P2,
    float* __restrict__ l1, float* __restrict__ l2,
    float* __restrict__ S1g, float* __restrict__ S2g,
    float* __restrict__ SL1, float* __restrict__ SL2)
{
  __shared__ float vstash[4][32][DD];   // 32 KB, wave-local slices
  __shared__ float ss1[4][64], ss2[4][64], sl1[4], sl2[4];
  const int t  = threadIdx.x;
  const int bh = blockIdx.x >> 4;
  const int ck = blockIdx.x & 15;
  const int d  = t & 63, g = t >> 6;
  const int r0 = ck*CKS + g*32;
  const float* Vb  = V + (size_t)(bh >> 3) * NN * DD;
  const float* sqb = sq + bh*NN;
  const unsigned short* ib = idxg + bh*NN;
  float a1 = 0.f, a2 = 0.f, s1 = 0.f, s2 = 0.f;
  #pragma unroll 8
  for (int rr = 0; rr < 32; rr++) {
    const int r = r0 + rr;
    const float qv = sqb[r];
    const float e1 = __expf(qv), e2 = __expf(0.01f*qv);
    const float v  = Vb[(size_t)ib[r]*DD + d];
    vstash[g][rr][d] = v;               // same-wave, in-order
    a1 += e1*v;  a2 += e2*v;  s1 += e1;  s2 += e2;
  }
  ss1[g][d] = a1;  ss2[g][d] = a2;
  if (d == 0) { sl1[g] = s1;  sl2[g] = s2; }
  __syncthreads();
  float o1 = 0.f, o2 = 0.f, lo1 = 0.f, lo2 = 0.f;
  for (int gg = 0; gg < g; gg++) { o1 += ss1[gg][d]; o2 += ss2[gg][d]; lo1 += sl1[gg]; lo2 += sl2[gg]; }
  if (g == 0) {   // chunk totals (now in d_ws — no d_out aliasing)
    S1g[(bh*NCK + ck)*64 + d] = ss1[0][d]+ss1[1][d]+ss1[2][d]+ss1[3][d];
    S2g[(bh*NCK + ck)*64 + d] = ss2[0][d]+ss2[1][d]+ss2[2][d]+ss2[3][d];
    if (d == 0) {
      SL1[bh*NCK + ck] = sl1[0]+sl1[1]+sl1[2]+sl1[3];
      SL2[bh*NCK + ck] = sl2[0]+sl2[1]+sl2[2]+sl2[3];
    }
  }
  // pass 2: exclusive chunk-local prefixes; V from LDS stash
  a1 = o1; a2 = o2; s1 = lo1; s2 = lo2;
  float* P1b = P1 + (size_t)bh*NN*DD;
  float* P2b = P2 + (size_t)bh*NN*DD;
  #pragma unroll 8
  for (int rr = 0; rr < 32; rr++) {
    const int r = r0 + rr;
    const float qv = sqb[r];
    const float e1 = __expf(qv), e2 = __expf(0.01f*qv);
    const float v  = vstash[g][rr][d];
    P1b[(size_t)r*DD + d] = a1;
    P2b[(size_t)r*DD + d] = a2;
    if (d == 0) { l1[bh*NN + r] = s1;  l2[bh*NN + r] = s2; }
    a1 += e1*v;  a2 += e2*v;  s1 += e1;  s2 += e2;
  }
}

// ------- Kernel 4: offsets-in-LDS preamble + 64-ary search + write ----------
__global__ __launch_bounds__(256) void k_out(
    const float* __restrict__ sq, const float* __restrict__ ksg,
    const float* __restrict__ P1, const float* __restrict__ P2,
    const float* __restrict__ S1g, const float* __restrict__ S2g,
    const float* __restrict__ SL1, const float* __restrict__ SL2,
    const float* __restrict__ l1, const float* __restrict__ l2,
    float* __restrict__ out)
{
  __shared__ float Of1[NCK + 1][64], Of2[NCK + 1][64];
  __shared__ float Lo1[NCK + 1], Lo2[NCK + 1];
  const int t   = threadIdx.x;
  const int bh  = blockIdx.x >> 7;                       // 32 bh x 128 blocks
  const int loc = blockIdx.x & 127;
  const int w   = t >> 6;
  const int d   = t & 63;                                // lane id
  const int i0  = loc*16 + w*4;                          // 4 i's per wave
  const int b   = bh >> 3, h = bh & 7;

  // preamble: exclusive prefix of the 16 chunk sums (L2-hot, redundant/block)
  if (t < 64) {
    float a = 0.f;
    for (int ck = 0; ck < NCK; ck++) {
      Of1[ck][t] = a;  a += S1g[(bh*NCK + ck)*64 + t];
    }
    Of1[NCK][t] = a;
  } else if (t < 128) {
    const int dd = t - 64;
    float a = 0.f;
    for (int ck = 0; ck < NCK; ck++) {
      Of2[ck][dd] = a;  a += S2g[(bh*NCK + ck)*64 + dd];
    }
    Of2[NCK][dd] = a;
  } else if (t == 128) {
    float a = 0.f;
    for (int ck = 0; ck < NCK; ck++) { Lo1[ck] = a;  a += SL1[bh*NCK + ck]; }
    Lo1[NCK] = a;
  } else if (t == 129) {
    float a = 0.f;
    for (int ck = 0; ck < NCK; ck++) { Lo2[ck] = a;  a += SL2[bh*NCK + ck]; }
    Lo2[NCK] = a;
  }
  __syncthreads();

  const float* s = sq + bh*NN;
  const float probe = s[d*32 + 31];                      // shared round-1 table
  const float T1  = Of1[NCK][d];
  const float Lt1 = Lo1[NCK];
  const size_t base = (size_t)bh * NN * DD;

  float kv[4], tt[4];
  int pos[4];
  #pragma unroll
  for (int u = 0; u < 4; u++) { kv[u] = ksg[bh*NN + i0 + u];  tt[u] = -kv[u]; }
  #pragma unroll
  for (int u = 0; u < 4; u++) {
    const unsigned long long m1 = __ballot(probe <= tt[u]);
    const int c1 = __popcll(m1);
    if (c1 == 64) pos[u] = NN;
    else {
      const unsigned long long m2 = __ballot(s[c1*32 + (d & 31)] <= tt[u]);
      pos[u] = c1*32 + (__popcll(m2) >> 1);
    }
  }
  #pragma unroll
  for (int u = 0; u < 4; u++) {
    const float ek  = __expf(kv[u]);
    const float ek2 = __expf(0.01f * kv[u]);
    float p1v, p2v, q1v, q2v;
    if (pos[u] < NN) {   // wave-uniform
      const int ch = pos[u] >> 7;
      p1v = P1[base + (size_t)pos[u]*DD + d] + Of1[ch][d];
      p2v = P2[base + (size_t)pos[u]*DD + d] + Of2[ch][d];
      q1v = l1[bh*NN + pos[u]] + Lo1[ch];
      q2v = l2[bh*NN + pos[u]] + Lo2[ch];
    } else {
      p1v = T1;   p2v = Of2[NCK][d];
      q1v = Lt1;  q2v = Lo2[NCK];
    }
    const float num = ek * (T1 - p1v)  + ek2 * p2v;
    const float den = ek * (Lt1 - q1v) + ek2 * q2v;
    out[((size_t)(b*NN + i0 + u)) * (HH*DD) + h*DD + d] = num / den;
  }
}

extern "C" void kernel_launch(void* const* d_in, const int* in_sizes, int n_in,
                              void* d_out, int out_size, void* d_ws, size_t ws_size,
                              hipStream_t stream)
{
  (void)in_sizes; (void)n_in; (void)out_size; (void)ws_size;
  const float* X  = (const float*)d_in[0];
  const float* Wv = (const float*)d_in[1];
  const float* bv = (const float*)d_in[2];
  const float* Wq = (const float*)d_in[3];
  const float* bq = (const float*)d_in[4];
  const float* Wk = (const float*)d_in[5];
  const float* bk = (const float*)d_in[6];
  float* out = (float*)d_out;

  // workspace carve-up (~38 MB, within proven budget)
  float* w = (float*)d_ws;
  float* V     = w;  w += (size_t)BB*NN*DD;        // 524288
  float* qsg   = w;  w += BH*NN;                   // raw q (unsorted)
  float* ksg   = w;  w += BH*NN;
  float* l1    = w;  w += BH*NN;
  float* l2    = w;  w += BH*NN;
  unsigned short* idxg = (unsigned short*)w;  w += BH*NN/2;
  float* S1g   = w;  w += (size_t)BH*NCK*DD;       // 32768 (in ws, not d_out)
  float* S2g   = w;  w += (size_t)BH*NCK*DD;
  float* SL1   = w;  w += BH*NCK;
  float* SL2   = w;  w += BH*NCK;
  float* sqs   = w;  w += BH*NN;                   // sorted q (rank-scattered)
  unsigned long long* qk64 = (unsigned long long*)w;  w += BH*NN*2;  // u64 keys
  float* P1    = w;  w += (size_t)BH*NN*DD;        // 16.8 MB
  float* P2    = w;  w += (size_t)BH*NN*DD;

  // V partials alias P1 (dead until k_scan): KSP x 2.1MB = 4.2 MB < sizeof(P1)
  float* Vpart = P1;

  k_v    <<<512, 256, 0, stream>>>(X, Wv, Vpart);
  k_vred <<<512, 256, 0, stream>>>(Vpart, bv, Wq, bq, Wk, bk, V, qsg, ksg, qk64);
  k_rank <<<BH*8, 256, 0, stream>>>(qk64, sqs, idxg);
  k_scan <<<BH*NCK, 256, 0, stream>>>(sqs, idxg, V, P1, P2, l1, l2, S1g, S2g, SL1, SL2);
  k_out  <<<BH*128, 256, 0, stream>>>(sqs, ksg, P1, P2, S1g, S2g, SL1, SL2, l1, l2, out);
}

// Round 3
// 133.657 us; speedup vs baseline: 1.4060x; 1.0150x over previous
//
#include <hip/hip_runtime.h>

// Problem constants (from reference): B=4, N=2048, IN_F=512, HEADS=8, D=64
#define BB   4
#define NN   2048
#define INF  512
#define HH   8
#define DD   64
#define BH   (BB*HH)   // 32
#define NCK  16        // 128-row chunks per (b,h)
#define CKS  128       // chunk size

// ============================================================================
// A[b,h,i,j] = softmax_j( leaky_relu(q_j + k_i) ), H = A @ V.
// exp(leaky(x)) is piecewise multiplicative; sort j by q_j and the softmax
// collapses to prefix sums + binary search. O(N·D).
// R9 calibration: LDS pipe is per-CU shared (~85B/cyc); GEMM LDS bytes/MAC
// = 4/rows_per_thread sets the floor. Harness 0xAA ws-poison (~87us) is
// inside dur_us, untouchable.
// R11 FAILED: SMEM-fed O(N^2) rank = 66us (1 wave/SIMD + per-iter lgkmcnt
// drain). R12: LDS-fed rank (16KB key stage, ds_read_b128 broadcast) ~5us.
// R13: k_v was 2B/MAC -> 24.6k LDS cyc/CU ~ 10.3us. New fused k_vq: 32-row
// blocks, 256 thr, in-block k-split (waves 0-1: k<256, waves 2-3: k>=256),
// thread = 4 rows x 4 cols -> 1B/MAC ~ 5.1us LDS floor; LDS-reduce the two
// k-halves, then scores q,k + u64 keys from LDS-resident V (k_vred fused,
// Vpart round-trip eliminated, one launch gap saved).
// ============================================================================

// ---- Kernel 1: fused V GEMM + q,k scores + sort keys -----------------------
// grid 256 x 256 thr. Block = 32 rows x 64 cols x full 512 k.
__global__ __launch_bounds__(256) void k_vq(
    const float* __restrict__ X, const float* __restrict__ Wv,
    const float* __restrict__ bv,
    const float* __restrict__ Wq, const float* __restrict__ bq,
    const float* __restrict__ Wk, const float* __restrict__ bk,
    float* __restrict__ V, float* __restrict__ qsg, float* __restrict__ ksg,
    unsigned long long* __restrict__ qk64)
{
  __shared__ float Ws[2][64][68];   // per-half W chunk [k][n], padded — 34.8KB
  __shared__ float red[128][16];    // kh=1 partial accs — 8KB
  __shared__ float Vs[32][65];      // reduced V rows for scores — 8.3KB
  const int t  = threadIdx.x;
  const int kh = t >> 7;            // k half: waves 0-1 -> 0, waves 2-3 -> 1
  const int u  = t & 127;
  const int tc = u & 15;            // col quad -> cols 4tc..4tc+3
  const int rg = u >> 4;            // row group -> rows 4rg..4rg+3
  const int r0 = blockIdx.x * 32;
  const int k0 = kh * 256;
  float acc[4][4];
  #pragma unroll
  for (int r = 0; r < 4; r++)
    #pragma unroll
    for (int c = 0; c < 4; c++) acc[r][c] = 0.f;

  for (int kc = 0; kc < 256; kc += 64) {
    __syncthreads();
    #pragma unroll
    for (int i = 0; i < 8; i++) {    // stage this half's 64k x 64n W chunk
      const int e4 = u + i * 128;    // 0..1023 float4 slots
      const int k  = e4 >> 4;
      const int n4 = (e4 & 15) * 4;
      *(float4*)(&Ws[kh][k][n4]) =
          *(const float4*)(Wv + (size_t)(k0 + kc + k) * DD + n4);
    }
    __syncthreads();
    const float* xp = X + (size_t)(r0 + rg * 4) * INF + k0 + kc;
    #pragma unroll 4
    for (int kk = 0; kk < 64; kk += 4) {
      float4 xr[4];
      #pragma unroll
      for (int r = 0; r < 4; r++)
        xr[r] = *(const float4*)(xp + (size_t)r * INF + kk);  // 16-lane bcast
      #pragma unroll
      for (int j = 0; j < 4; j++) {
        const float4 w4 = *(const float4*)(&Ws[kh][kk + j][tc * 4]);
        #pragma unroll
        for (int r = 0; r < 4; r++) {
          const float x = (j == 0) ? xr[r].x : (j == 1) ? xr[r].y
                        : (j == 2) ? xr[r].z : xr[r].w;
          acc[r][0] += x * w4.x;  acc[r][1] += x * w4.y;
          acc[r][2] += x * w4.z;  acc[r][3] += x * w4.w;
        }
      }
    }
  }

  // ---- reduce the two k-halves, add bias, publish V (global + LDS) ----
  __syncthreads();
  if (kh == 1) {
    #pragma unroll
    for (int r = 0; r < 4; r++)
      *(float4*)(&red[u][r * 4]) = *(const float4*)(&acc[r][0]);
  }
  __syncthreads();
  if (kh == 0) {
    const float4 bb = *(const float4*)(bv + tc * 4);
    #pragma unroll
    for (int r = 0; r < 4; r++) {
      const float4 p = *(const float4*)(&red[u][r * 4]);
      float4 o;
      o.x = acc[r][0] + p.x + bb.x;  o.y = acc[r][1] + p.y + bb.y;
      o.z = acc[r][2] + p.z + bb.z;  o.w = acc[r][3] + p.w + bb.w;
      *(float4*)(V + (size_t)(r0 + rg * 4 + r) * DD + tc * 4) = o;
      Vs[rg * 4 + r][tc * 4]     = o.x;  Vs[rg * 4 + r][tc * 4 + 1] = o.y;
      Vs[rg * 4 + r][tc * 4 + 2] = o.z;  Vs[rg * 4 + r][tc * 4 + 3] = o.w;
    }
  }
  __syncthreads();

  // ---- scores: thread = (row, h), does both q and k dot-64 ----
  const int row = t >> 3;
  const int h   = t & 7;
  float sq = bq[h], sk = bk[h];
  #pragma unroll 8
  for (int dd = 0; dd < DD; dd++) {
    const float v = Vs[row][dd];
    sq += v * Wq[dd * HH + h];
    sk += v * Wk[dd * HH + h];
  }
  const int grow = r0 + row;
  const int b = grow >> 11, n = grow & (NN - 1);
  const int bh = b * HH + h;
  qsg[bh * NN + n] = sq;
  ksg[bh * NN + n] = sk;
  // tie-proof orderable key: ascending u64 order == ascending (float, idx)
  unsigned uo = __float_as_uint(sq);
  uo = (uo & 0x80000000u) ? ~uo : (uo | 0x80000000u);
  qk64[(size_t)bh * NN + n] = ((unsigned long long)uo << 32) | (unsigned)n;
}

// -------- Kernel 2: LDS-fed O(N^2) rank + scatter ---------------------------
// 256 blocks x 256 threads. Block = (bh, 256-j slab). Stage all 2048 keys in
// LDS (16KB); thread = (jq = t&63 -> 4 consecutive j's, kq = t>>6 -> 512-key
// quarter). Broadcast ds_read_b128 (2 keys) feeds 8 u64-cmps -> VALU-bound.
// Partial counts combined via LDS, wave 0 scatters. q recovered from key.
__global__ __launch_bounds__(256) void k_rank(
    const unsigned long long* __restrict__ qk64,
    float* __restrict__ sqs, unsigned short* __restrict__ idxg)
{
  __shared__ __align__(16) unsigned long long keys[NN];  // 16 KB
  __shared__ int cnt[4][256];                            // 4 KB
  const int t  = threadIdx.x;
  const int bh = blockIdx.x >> 3;
  const int jq = t & 63;
  const int kq = t >> 6;
  const unsigned long long* __restrict__ kb = qk64 + (size_t)bh * NN;

  // stage: 1024 x 16B, coalesced
  {
    const ulonglong2* __restrict__ g2 = (const ulonglong2*)kb;
    ulonglong2* s2 = (ulonglong2*)keys;
    #pragma unroll
    for (int x = 0; x < 4; x++) s2[t + 256 * x] = g2[t + 256 * x];
  }
  __syncthreads();

  const int jg = ((blockIdx.x & 7) << 8) | (jq << 2);    // first of 4 j's
  const unsigned long long kj0 = keys[jg];
  const unsigned long long kj1 = keys[jg + 1];
  const unsigned long long kj2 = keys[jg + 2];
  const unsigned long long kj3 = keys[jg + 3];

  const ulonglong2* __restrict__ k2 = (const ulonglong2*)(keys + kq * 512);
  int c0 = 0, c1 = 0, c2 = 0, c3 = 0;
  #pragma unroll 8
  for (int l = 0; l < 256; l++) {            // 512 keys, 2 per b128
    const ulonglong2 kk = k2[l];
    c0 += (kk.x < kj0) + (kk.y < kj0);
    c1 += (kk.x < kj1) + (kk.y < kj1);
    c2 += (kk.x < kj2) + (kk.y < kj2);
    c3 += (kk.x < kj3) + (kk.y < kj3);
  }
  cnt[kq][0 * 64 + jq] = c0;   // [u*64+jq]: lane-stride-1, conflict-free
  cnt[kq][1 * 64 + jq] = c1;
  cnt[kq][2 * 64 + jq] = c2;
  cnt[kq][3 * 64 + jq] = c3;
  __syncthreads();

  if (kq == 0) {
    #pragma unroll
    for (int u = 0; u < 4; u++) {
      const int rank = cnt[0][u * 64 + jq] + cnt[1][u * 64 + jq]
                     + cnt[2][u * 64 + jq] + cnt[3][u * 64 + jq];
      const unsigned long long kj = keys[jg + u];
      const unsigned uo = (unsigned)(kj >> 32);
      const unsigned ur = (uo & 0x80000000u) ? (uo & 0x7fffffffu) : ~uo;
      sqs [bh * NN + rank] = __uint_as_float(ur);
      idxg[bh * NN + rank] = (unsigned short)(jg + u);
    }
  }
}

// -------- Kernel 3: hierarchical scan — chunk-local prefixes + chunk sums ----
__global__ __launch_bounds__(256) void k_scan(
    const float* __restrict__ sq, const unsigned short* __restrict__ idxg,
    const float* __restrict__ V,
    float* __restrict__ P1, float* __restrict__ P2,
    float* __restrict__ l1, float* __restrict__ l2,
    float* __restrict__ S1g, float* __restrict__ S2g,
    float* __restrict__ SL1, float* __restrict__ SL2)
{
  __shared__ float vstash[4][32][DD];   // 32 KB, wave-local slices
  __shared__ float ss1[4][64], ss2[4][64], sl1[4], sl2[4];
  const int t  = threadIdx.x;
  const int bh = blockIdx.x >> 4;
  const int ck = blockIdx.x & 15;
  const int d  = t & 63, g = t >> 6;
  const int r0 = ck*CKS + g*32;
  const float* Vb  = V + (size_t)(bh >> 3) * NN * DD;
  const float* sqb = sq + bh*NN;
  const unsigned short* ib = idxg + bh*NN;
  float a1 = 0.f, a2 = 0.f, s1 = 0.f, s2 = 0.f;
  #pragma unroll 8
  for (int rr = 0; rr < 32; rr++) {
    const int r = r0 + rr;
    const float qv = sqb[r];
    const float e1 = __expf(qv), e2 = __expf(0.01f*qv);
    const float v  = Vb[(size_t)ib[r]*DD + d];
    vstash[g][rr][d] = v;               // same-wave, in-order
    a1 += e1*v;  a2 += e2*v;  s1 += e1;  s2 += e2;
  }
  ss1[g][d] = a1;  ss2[g][d] = a2;
  if (d == 0) { sl1[g] = s1;  sl2[g] = s2; }
  __syncthreads();
  float o1 = 0.f, o2 = 0.f, lo1 = 0.f, lo2 = 0.f;
  for (int gg = 0; gg < g; gg++) { o1 += ss1[gg][d]; o2 += ss2[gg][d]; lo1 += sl1[gg]; lo2 += sl2[gg]; }
  if (g == 0) {   // chunk totals
    S1g[(bh*NCK + ck)*64 + d] = ss1[0][d]+ss1[1][d]+ss1[2][d]+ss1[3][d];
    S2g[(bh*NCK + ck)*64 + d] = ss2[0][d]+ss2[1][d]+ss2[2][d]+ss2[3][d];
    if (d == 0) {
      SL1[bh*NCK + ck] = sl1[0]+sl1[1]+sl1[2]+sl1[3];
      SL2[bh*NCK + ck] = sl2[0]+sl2[1]+sl2[2]+sl2[3];
    }
  }
  // pass 2: exclusive chunk-local prefixes; V from LDS stash
  a1 = o1; a2 = o2; s1 = lo1; s2 = lo2;
  float* P1b = P1 + (size_t)bh*NN*DD;
  float* P2b = P2 + (size_t)bh*NN*DD;
  #pragma unroll 8
  for (int rr = 0; rr < 32; rr++) {
    const int r = r0 + rr;
    const float qv = sqb[r];
    const float e1 = __expf(qv), e2 = __expf(0.01f*qv);
    const float v  = vstash[g][rr][d];
    P1b[(size_t)r*DD + d] = a1;
    P2b[(size_t)r*DD + d] = a2;
    if (d == 0) { l1[bh*NN + r] = s1;  l2[bh*NN + r] = s2; }
    a1 += e1*v;  a2 += e2*v;  s1 += e1;  s2 += e2;
  }
}

// ------- Kernel 4: offsets-in-LDS preamble + 64-ary search + write ----------
__global__ __launch_bounds__(256) void k_out(
    const float* __restrict__ sq, const float* __restrict__ ksg,
    const float* __restrict__ P1, const float* __restrict__ P2,
    const float* __restrict__ S1g, const float* __restrict__ S2g,
    const float* __restrict__ SL1, const float* __restrict__ SL2,
    const float* __restrict__ l1, const float* __restrict__ l2,
    float* __restrict__ out)
{
  __shared__ float Of1[NCK + 1][64], Of2[NCK + 1][64];
  __shared__ float Lo1[NCK + 1], Lo2[NCK + 1];
  const int t   = threadIdx.x;
  const int bh  = blockIdx.x >> 7;                       // 32 bh x 128 blocks
  const int loc = blockIdx.x & 127;
  const int w   = t >> 6;
  const int d   = t & 63;                                // lane id
  const int i0  = loc*16 + w*4;                          // 4 i's per wave
  const int b   = bh >> 3, h = bh & 7;

  // preamble: exclusive prefix of the 16 chunk sums (L2-hot, redundant/block)
  if (t < 64) {
    float a = 0.f;
    for (int ck = 0; ck < NCK; ck++) {
      Of1[ck][t] = a;  a += S1g[(bh*NCK + ck)*64 + t];
    }
    Of1[NCK][t] = a;
  } else if (t < 128) {
    const int dd = t - 64;
    float a = 0.f;
    for (int ck = 0; ck < NCK; ck++) {
      Of2[ck][dd] = a;  a += S2g[(bh*NCK + ck)*64 + dd];
    }
    Of2[NCK][dd] = a;
  } else if (t == 128) {
    float a = 0.f;
    for (int ck = 0; ck < NCK; ck++) { Lo1[ck] = a;  a += SL1[bh*NCK + ck]; }
    Lo1[NCK] = a;
  } else if (t == 129) {
    float a = 0.f;
    for (int ck = 0; ck < NCK; ck++) { Lo2[ck] = a;  a += SL2[bh*NCK + ck]; }
    Lo2[NCK] = a;
  }
  __syncthreads();

  const float* s = sq + bh*NN;
  const float probe = s[d*32 + 31];                      // shared round-1 table
  const float T1  = Of1[NCK][d];
  const float Lt1 = Lo1[NCK];
  const size_t base = (size_t)bh * NN * DD;

  float kv[4], tt[4];
  int pos[4];
  #pragma unroll
  for (int u = 0; u < 4; u++) { kv[u] = ksg[bh*NN + i0 + u];  tt[u] = -kv[u]; }
  #pragma unroll
  for (int u = 0; u < 4; u++) {
    const unsigned long long m1 = __ballot(probe <= tt[u]);
    const int c1 = __popcll(m1);
    if (c1 == 64) pos[u] = NN;
    else {
      const unsigned long long m2 = __ballot(s[c1*32 + (d & 31)] <= tt[u]);
      pos[u] = c1*32 + (__popcll(m2) >> 1);
    }
  }
  #pragma unroll
  for (int u = 0; u < 4; u++) {
    const float ek  = __expf(kv[u]);
    const float ek2 = __expf(0.01f * kv[u]);
    float p1v, p2v, q1v, q2v;
    if (pos[u] < NN) {   // wave-uniform
      const int ch = pos[u] >> 7;
      p1v = P1[base + (size_t)pos[u]*DD + d] + Of1[ch][d];
      p2v = P2[base + (size_t)pos[u]*DD + d] + Of2[ch][d];
      q1v = l1[bh*NN + pos[u]] + Lo1[ch];
      q2v = l2[bh*NN + pos[u]] + Lo2[ch];
    } else {
      p1v = T1;   p2v = Of2[NCK][d];
      q1v = Lt1;  q2v = Lo2[NCK];
    }
    const float num = ek * (T1 - p1v)  + ek2 * p2v;
    const float den = ek * (Lt1 - q1v) + ek2 * q2v;
    out[((size_t)(b*NN + i0 + u)) * (HH*DD) + h*DD + d] = num / den;
  }
}

extern "C" void kernel_launch(void* const* d_in, const int* in_sizes, int n_in,
                              void* d_out, int out_size, void* d_ws, size_t ws_size,
                              hipStream_t stream)
{
  (void)in_sizes; (void)n_in; (void)out_size; (void)ws_size;
  const float* X  = (const float*)d_in[0];
  const float* Wv = (const float*)d_in[1];
  const float* bv = (const float*)d_in[2];
  const float* Wq = (const float*)d_in[3];
  const float* bq = (const float*)d_in[4];
  const float* Wk = (const float*)d_in[5];
  const float* bk = (const float*)d_in[6];
  float* out = (float*)d_out;

  // workspace carve-up (~38 MB, within proven budget)
  float* w = (float*)d_ws;
  float* V     = w;  w += (size_t)BB*NN*DD;        // 524288
  float* qsg   = w;  w += BH*NN;                   // raw q (unsorted)
  float* ksg   = w;  w += BH*NN;
  float* l1    = w;  w += BH*NN;
  float* l2    = w;  w += BH*NN;
  unsigned short* idxg = (unsigned short*)w;  w += BH*NN/2;
  float* S1g   = w;  w += (size_t)BH*NCK*DD;       // 32768 (in ws, not d_out)
  float* S2g   = w;  w += (size_t)BH*NCK*DD;
  float* SL1   = w;  w += BH*NCK;
  float* SL2   = w;  w += BH*NCK;
  float* sqs   = w;  w += BH*NN;                   // sorted q (rank-scattered)
  unsigned long long* qk64 = (unsigned long long*)w;  w += BH*NN*2;  // u64 keys
  float* P1    = w;  w += (size_t)BH*NN*DD;        // 16.8 MB
  float* P2    = w;  w += (size_t)BH*NN*DD;

  k_vq   <<<256, 256, 0, stream>>>(X, Wv, bv, Wq, bq, Wk, bk, V, qsg, ksg, qk64);
  k_rank <<<BH*8, 256, 0, stream>>>(qk64, sqs, idxg);
  k_scan <<<BH*NCK, 256, 0, stream>>>(sqs, idxg, V, P1, P2, l1, l2, S1g, S2g, SL1, SL2);
  k_out  <<<BH*128, 256, 0, stream>>>(sqs, ksg, P1, P2, S1g, S2g, SL1, SL2, l1, l2, out);
}